// Round 4
// baseline (139.084 us; speedup 1.0000x reference)
//
#include <hip/hip_runtime.h>

// CREStereo grouped correlation, round 16.
// R15 post-mortem: inline meta worked (143.1 -> 138.6us, predicted 137-139).
// Top-5 all harness fills (81.3us fixed). Controllable ~57us: prepass ~20,
// corr ~29-33, gaps. Corr floors: TD 17.8us, per-XCD L2 20.3us -> corr at
// ~70% of L2 floor.
// R16 theory: block's 4 waves drift out of k-phase; the union tap footprint
// (~75KB) thrashes the 32KB L1 so every tap read goes to L2. Phase-locking
// the block with __syncthreads() before each k-batch's load issue shrinks
// the instantaneous footprint to ~20KB (fits L1) -> block's 288 tap-row
// reads mostly L1-hit -> L2 traffic drops below its 20.3us floor.
// Single-variable change: 2 barriers in corr k-loop. Everything else frozen.

namespace {
constexpr int kB = 2;
constexpr int kC = 256;
constexpr int kH = 96;
constexpr int kW = 192;
constexpr int kG = 4;
constexpr int kGC = kC / kG;              // 64
constexpr int kK = 9;
constexpr int kHW = kH * kW;              // 18432
constexpr size_t kPlane = (size_t)kC * kHW;
constexpr int kTransBlocks = (kHW / 64) * (kC / 64) * kB * 2;   // 4608
constexpr int kCorrBlocks  = kB * kHW / 8;                      // 4608 (8 px/block)
}

typedef _Float16 half8_t __attribute__((ext_vector_type(8)));
typedef _Float16 half4_t __attribute__((ext_vector_type(4)));
typedef _Float16 half2_t __attribute__((ext_vector_type(2)));

struct TapMeta {        // 32 B: one (b,px,k) candidate
  int4   off;           // element offsets of 4 taps into right_t plane
  float4 wgt;           // bilinear weights (validity folded in)
};

__device__ __forceinline__ float dot8(half8_t a, half8_t b, float acc) {
#if __has_builtin(__builtin_amdgcn_fdot2)
  #pragma unroll
  for (int i = 0; i < 4; ++i) {
    half2_t a2 = {a[2 * i], a[2 * i + 1]};
    half2_t b2 = {b[2 * i], b[2 * i + 1]};
    acc = __builtin_amdgcn_fdot2(a2, b2, acc, false);
  }
#else
  #pragma unroll
  for (int i = 0; i < 8; ++i) acc += (float)a[i] * (float)b[i];
#endif
  return acc;
}

// ---- pre-pass: pure fp32->fp16 64x64 transpose, 4608 blocks ----
__global__ __launch_bounds__(256) void prepass_kernel(
    const float* __restrict__ left, const float* __restrict__ right,
    _Float16* __restrict__ left_t, _Float16* __restrict__ right_t)
{
  __shared__ float tile[64][65];
  int tb = blockIdx.x;
  int pt = tb % (kHW / 64);         // pixel tile 0..287
  int ct = (tb / (kHW / 64)) % 4;   // channel tile 0..3
  int z  = tb / ((kHW / 64) * 4);   // b*2 + tensor
  int b  = z >> 1;
  const float* in = (z & 1) ? right : left;
  _Float16*   dst = (z & 1) ? right_t : left_t;
  int p0 = pt * 64, c0 = ct * 64;
  const float* inb = in + (size_t)b * kPlane;
  _Float16*   outb = dst + (size_t)b * kPlane;
  int t = threadIdx.x;
  int cl = t >> 2;
  int q  = t & 3;
  #pragma unroll
  for (int i = 0; i < 4; ++i) {
    int j = q + 4 * i;
    float4 v = *(const float4*)(inb + (size_t)(c0 + cl) * kHW + p0 + 4 * j);
    tile[cl][4 * j + 0] = v.x;
    tile[cl][4 * j + 1] = v.y;
    tile[cl][4 * j + 2] = v.z;
    tile[cl][4 * j + 3] = v.w;
  }
  __syncthreads();
  // write stage: half8 per lane -> each pixel's 64-ch chunk is one 128B
  // contiguous run written by 8 consecutive lanes (full cache lines).
  int pl8 = t >> 3;                 // pixel 0..31 (+32*i)
  int c8  = t & 7;                  // channel octet
  #pragma unroll
  for (int i = 0; i < 2; ++i) {
    int px = pl8 + 32 * i;
    half8_t hv;
    #pragma unroll
    for (int j = 0; j < 8; ++j)
      hv[j] = (_Float16)tile[8 * c8 + j][px];
    *(half8_t*)(outb + (size_t)(p0 + px) * kC + c0 + 8 * c8) = hv;
  }
}

// ---- main: block = 8 px; wave = 2 px x 32 lanes; lane owns 8 ch ----
// TapMeta computed inline (72 threads -> LDS); XCD-chunked swizzle;
// R16: k-batches phase-locked across the block's 4 waves (L1 reuse).
__global__ __launch_bounds__(256) void corr_fp16_kernel(
    const _Float16* __restrict__ left_t, const _Float16* __restrict__ right_t,
    const float* __restrict__ flow, const float* __restrict__ extra,
    float* __restrict__ out)
{
  __shared__ TapMeta smeta[8 * kK];     // 8 px * 9 k * 32 B = 2304 B

  // XCD-chunked swizzle: 4608 blocks -> XCD i owns blocks [i*576,(i+1)*576).
  int sb = (blockIdx.x & 7) * (kCorrBlocks / 8) + (blockIdx.x >> 3);
  int blockPix = sb * 8;                // first of 8 pixels (global, b-major)
  int b    = blockPix / kHW;            // blocks never straddle batch
  int pix0 = blockPix % kHW;

  int wv   = threadIdx.x >> 6;          // wave in block 0..3
  int lane = threadIdx.x & 63;
  int p    = lane >> 5;                 // pixel cluster 0..1
  int cl   = lane & 31;                 // channel-lane: owns channels cl*8..cl*8+7
  int pix  = pix0 + wv * 2 + p;

  // issue left load early (independent of meta)
  half8_t l8 = *(const half8_t*)(left_t + ((size_t)b * kHW + pix) * kC + cl * 8);

  // inline meta: thread t<72 computes TapMeta for (px = t/9, k = t%9).
  int t = threadIdx.x;
  if (t < 8 * kK) {
    int px = t / kK;
    int k  = t - px * kK;
    int gpix = pix0 + px;
    int w = gpix % kW, h = gpix / kW;

    const float* flowb = flow + (size_t)b * 2 * kHW + gpix;
    float bx = (float)w + flowb[0];
    float by = (float)h + flowb[kHW];
    const float* extb = extra + (size_t)b * 2 * kK * kHW + gpix;

    float xx = bx + (float)(k - 4) + extb[(size_t)(2 * k) * kHW];
    float yy = by + extb[(size_t)(2 * k + 1) * kHW];
    float xf = floorf(xx), yf = floorf(yy);
    float fx = xx - xf, fy = yy - yf;
    int ix0 = (int)xf, iy0 = (int)yf;
    int ix1 = ix0 + 1, iy1 = iy0 + 1;
    bool vx0 = (ix0 >= 0) && (ix0 < kW);
    bool vx1 = (ix1 >= 0) && (ix1 < kW);
    bool vy0 = (iy0 >= 0) && (iy0 < kH);
    bool vy1 = (iy1 >= 0) && (iy1 < kH);
    int xc0 = min(max(ix0, 0), kW - 1);
    int xc1 = min(max(ix1, 0), kW - 1);
    int yc0 = min(max(iy0, 0), kH - 1);
    int yc1 = min(max(iy1, 0), kH - 1);
    float wx0 = 1.f - fx, wy0 = 1.f - fy;
    TapMeta m;
    m.off.x = (yc0 * kW + xc0) * kC;
    m.off.y = (yc0 * kW + xc1) * kC;
    m.off.z = (yc1 * kW + xc0) * kC;
    m.off.w = (yc1 * kW + xc1) * kC;
    m.wgt.x = wx0 * wy0 * ((vx0 && vy0) ? 1.f : 0.f);
    m.wgt.y = fx  * wy0 * ((vx1 && vy0) ? 1.f : 0.f);
    m.wgt.z = wx0 * fy  * ((vx0 && vy1) ? 1.f : 0.f);
    m.wgt.w = fx  * fy  * ((vx1 && vy1) ? 1.f : 0.f);
    smeta[t] = m;
  }

  const _Float16* Rb = right_t + (size_t)b * kPlane + cl * 8;

  __syncthreads();
  const TapMeta* mp = smeta + (wv * 2 + p) * kK;   // LDS, broadcast reads

  float rr[kK];

  #pragma unroll
  for (int kb = 0; kb < kK; kb += 3) {
    // R16: phase-lock the block's 4 waves at each k-batch so their tap
    // footprints coincide in time (~20KB, fits 32KB L1 -> intra-block
    // reuse becomes L1 hits instead of L2 traffic).
    if (kb > 0) __syncthreads();
    int4   off[3];
    float4 wv4[3];
    #pragma unroll
    for (int j = 0; j < 3; ++j) {
      off[j] = mp[kb + j].off;
      wv4[j] = mp[kb + j].wgt;
    }
    half8_t tp[3][4];
    #pragma unroll
    for (int j = 0; j < 3; ++j) {
      tp[j][0] = *(const half8_t*)(Rb + off[j].x);
      tp[j][1] = *(const half8_t*)(Rb + off[j].y);
      tp[j][2] = *(const half8_t*)(Rb + off[j].z);
      tp[j][3] = *(const half8_t*)(Rb + off[j].w);
    }
    #pragma unroll
    for (int j = 0; j < 3; ++j) {
      float d00 = dot8(tp[j][0], l8, 0.f);
      float d01 = dot8(tp[j][1], l8, 0.f);
      float d10 = dot8(tp[j][2], l8, 0.f);
      float d11 = dot8(tp[j][3], l8, 0.f);
      float r = wv4[j].x * d00 + wv4[j].y * d01 + wv4[j].z * d10 + wv4[j].w * d11;
      r += __shfl_xor(r, 1);
      r += __shfl_xor(r, 2);
      r += __shfl_xor(r, 4);
      rr[kb + j] = r;           // all lanes hold the group sum
    }
  }

  // single masked store block: exec mask changes once
  int g = cl >> 3;
  if ((cl & 7) == 0) {
    float* outp = out + ((size_t)b * kG + g) * kK * kHW + pix;
    #pragma unroll
    for (int k = 0; k < kK; ++k)
      outp[(size_t)k * kHW] = rr[k] * (1.f / kGC);
  }
}

// ---- fallback (round-2 kernel) if workspace too small ----
__global__ __launch_bounds__(256) void crestereo_corr_fallback(
    const float* __restrict__ left, const float* __restrict__ right,
    const float* __restrict__ flow, const float* __restrict__ extra,
    float* __restrict__ out)
{
  int t = blockIdx.x * blockDim.x + threadIdx.x;
  int w = t % kW;
  int h = (t / kW) % kH;
  int k = (t / kHW) % kK;
  int g = (t / (kHW * kK)) % kG;
  int b = t / (kHW * kK * kG);

  int pix = h * kW + w;
  const float* flowb = flow + b * 2 * kHW + pix;
  float x = (float)(w + (k - 4)) + flowb[0];
  float y = (float)h + flowb[kHW];
  const float* extb = extra + (size_t)(b * 2 * kK + 2 * k) * kHW + pix;
  x += extb[0];
  y += extb[kHW];

  float xf = floorf(x), yf = floorf(y);
  float fx = x - xf, fy = y - yf;
  int ix0 = (int)xf, iy0 = (int)yf;
  int ix1 = ix0 + 1, iy1 = iy0 + 1;
  bool vx0 = (ix0 >= 0) && (ix0 < kW);
  bool vx1 = (ix1 >= 0) && (ix1 < kW);
  bool vy0 = (iy0 >= 0) && (iy0 < kH);
  bool vy1 = (iy1 >= 0) && (iy1 < kH);
  int xc0 = min(max(ix0, 0), kW - 1);
  int xc1 = min(max(ix1, 0), kW - 1);
  int yc0 = min(max(iy0, 0), kH - 1);
  int yc1 = min(max(iy1, 0), kH - 1);
  float wx0 = 1.f - fx, wy0 = 1.f - fy;
  float w00 = wx0 * wy0 * ((vx0 && vy0) ? 1.f : 0.f);
  float w01 = fx  * wy0 * ((vx1 && vy0) ? 1.f : 0.f);
  float w10 = wx0 * fy  * ((vx0 && vy1) ? 1.f : 0.f);
  float w11 = fx  * fy  * ((vx1 && vy1) ? 1.f : 0.f);
  int idx = yc0 * kW + xc0;
  int dx  = xc1 - xc0;
  int dyw = (yc1 - yc0) * kW;

  const float* Rb = right + (size_t)(b * kC + g * kGC) * kHW + idx;
  const float* Lb = left  + (size_t)(b * kC + g * kGC) * kHW + pix;

  float acc = 0.f;
  #pragma unroll 4
  for (int c = 0; c < kGC; ++c) {
    const float* Rc = Rb + (size_t)c * kHW;
    float l   = Lb[(size_t)c * kHW];
    acc += l * (w00 * Rc[0] + w01 * Rc[dx] + w10 * Rc[dyw] + w11 * Rc[dx + dyw]);
  }
  out[(size_t)((b * kG + g) * kK + k) * kHW + pix] = acc * (1.f / kGC);
}

extern "C" void kernel_launch(void* const* d_in, const int* in_sizes, int n_in,
                              void* d_out, int out_size, void* d_ws, size_t ws_size,
                              hipStream_t stream) {
  const float* left  = (const float*)d_in[0];
  const float* right = (const float*)d_in[1];
  const float* flow  = (const float*)d_in[2];
  const float* extra = (const float*)d_in[3];
  float* out = (float*)d_out;

  size_t t_bytes = 2 * (size_t)kB * kPlane * sizeof(_Float16);   // 37.7 MB
  if (ws_size >= t_bytes) {
    _Float16* left_t  = (_Float16*)d_ws;
    _Float16* right_t = left_t + (size_t)kB * kPlane;

    prepass_kernel<<<kTransBlocks, 256, 0, stream>>>(left, right, left_t, right_t);
    corr_fp16_kernel<<<kCorrBlocks, 256, 0, stream>>>(
        left_t, right_t, flow, extra, out);
  } else {
    int total = kB * kG * kK * kH * kW;
    crestereo_corr_fallback<<<(total + 255) / 256, 256, 0, stream>>>(
        left, right, flow, extra, out);
  }
}

// Round 5
// 138.102 us; speedup vs baseline: 1.0071x; 1.0071x over previous
//
#include <hip/hip_runtime.h>

// CREStereo grouped correlation, round 17.
// R16 post-mortem: phase-lock barriers NEUTRAL (138.6 -> 139.1) -> L1-reuse
// theory dead (waves already in-phase or TD serves L1 hits). Reverted.
// R17: remove left from the prepass entirely. corr's 8 block-pixels are
// consecutive in one image row, so corr gathers left natively (thread t =
// channel t, 2xfloat4 = 32B contiguous), converts to fp16, redistributes
// via 4KB LDS. Prepass transposes right only: 4608 -> 2304 blocks,
// traffic 113 -> 56.6 MB (~-10us). Corr pays ~+2-3us (TD overfetch 2:1 on
// left + LDS round-trip). Predict total ~131.
// absmax bit-identical: same f32->f16 RNE cvt, same dot order.

namespace {
constexpr int kB = 2;
constexpr int kC = 256;
constexpr int kH = 96;
constexpr int kW = 192;
constexpr int kG = 4;
constexpr int kGC = kC / kG;              // 64
constexpr int kK = 9;
constexpr int kHW = kH * kW;              // 18432
constexpr size_t kPlane = (size_t)kC * kHW;
constexpr int kTransBlocks = (kHW / 64) * (kC / 64) * kB;       // 2304 (right only)
constexpr int kCorrBlocks  = kB * kHW / 8;                      // 4608 (8 px/block)
}

typedef _Float16 half8_t __attribute__((ext_vector_type(8)));
typedef _Float16 half4_t __attribute__((ext_vector_type(4)));
typedef _Float16 half2_t __attribute__((ext_vector_type(2)));

struct TapMeta {        // 32 B: one (b,px,k) candidate
  int4   off;           // element offsets of 4 taps into right_t plane
  float4 wgt;           // bilinear weights (validity folded in)
};

__device__ __forceinline__ float dot8(half8_t a, half8_t b, float acc) {
#if __has_builtin(__builtin_amdgcn_fdot2)
  #pragma unroll
  for (int i = 0; i < 4; ++i) {
    half2_t a2 = {a[2 * i], a[2 * i + 1]};
    half2_t b2 = {b[2 * i], b[2 * i + 1]};
    acc = __builtin_amdgcn_fdot2(a2, b2, acc, false);
  }
#else
  #pragma unroll
  for (int i = 0; i < 8; ++i) acc += (float)a[i] * (float)b[i];
#endif
  return acc;
}

// ---- pre-pass: fp32->fp16 64x64 transpose of RIGHT only, 2304 blocks ----
__global__ __launch_bounds__(256) void prepass_kernel(
    const float* __restrict__ right, _Float16* __restrict__ right_t)
{
  __shared__ float tile[64][65];
  int tb = blockIdx.x;
  int pt = tb % (kHW / 64);         // pixel tile 0..287
  int ct = (tb / (kHW / 64)) % 4;   // channel tile 0..3
  int b  = tb / ((kHW / 64) * 4);   // batch
  int p0 = pt * 64, c0 = ct * 64;
  const float* inb = right + (size_t)b * kPlane;
  _Float16*   outb = right_t + (size_t)b * kPlane;
  int t = threadIdx.x;
  int cl = t >> 2;
  int q  = t & 3;
  #pragma unroll
  for (int i = 0; i < 4; ++i) {
    int j = q + 4 * i;
    float4 v = *(const float4*)(inb + (size_t)(c0 + cl) * kHW + p0 + 4 * j);
    tile[cl][4 * j + 0] = v.x;
    tile[cl][4 * j + 1] = v.y;
    tile[cl][4 * j + 2] = v.z;
    tile[cl][4 * j + 3] = v.w;
  }
  __syncthreads();
  // write stage: half8 per lane -> each pixel's 64-ch chunk is one 128B
  // contiguous run written by 8 consecutive lanes (full cache lines).
  int pl8 = t >> 3;                 // pixel 0..31 (+32*i)
  int c8  = t & 7;                  // channel octet
  #pragma unroll
  for (int i = 0; i < 2; ++i) {
    int px = pl8 + 32 * i;
    half8_t hv;
    #pragma unroll
    for (int j = 0; j < 8; ++j)
      hv[j] = (_Float16)tile[8 * c8 + j][px];
    *(half8_t*)(outb + (size_t)(p0 + px) * kC + c0 + 8 * c8) = hv;
  }
}

// ---- main: block = 8 px; wave = 2 px x 32 lanes; lane owns 8 ch ----
// TapMeta inline (72 threads -> LDS); left gathered natively + LDS
// transpose (no left_t); XCD-chunked swizzle.
__global__ __launch_bounds__(256) void corr_fp16_kernel(
    const _Float16* __restrict__ right_t, const float* __restrict__ left,
    const float* __restrict__ flow, const float* __restrict__ extra,
    float* __restrict__ out)
{
  __shared__ TapMeta smeta[8 * kK];         // 2304 B
  __shared__ _Float16 smleft[8][kC];        // 8 px x 256 ch fp16 = 4 KB

  // XCD-chunked swizzle: 4608 blocks -> XCD i owns blocks [i*576,(i+1)*576).
  int sb = (blockIdx.x & 7) * (kCorrBlocks / 8) + (blockIdx.x >> 3);
  int blockPix = sb * 8;                // first of 8 pixels (global, b-major)
  int b    = blockPix / kHW;            // blocks never straddle batch
  int pix0 = blockPix % kHW;            // 8-aligned; W%8==0 -> same image row

  int t = threadIdx.x;

  // left native gather: thread t = channel t, 8 consecutive px = 32 B.
  const float* Lb = left + (size_t)b * kPlane + (size_t)t * kHW + pix0;
  float4 lv0 = *(const float4*)(Lb);
  float4 lv1 = *(const float4*)(Lb + 4);

  // inline meta: thread t<72 computes TapMeta for (px = t/9, k = t%9).
  if (t < 8 * kK) {
    int px = t / kK;
    int k  = t - px * kK;
    int gpix = pix0 + px;
    int w = gpix % kW, h = gpix / kW;

    const float* flowb = flow + (size_t)b * 2 * kHW + gpix;
    float bx = (float)w + flowb[0];
    float by = (float)h + flowb[kHW];
    const float* extb = extra + (size_t)b * 2 * kK * kHW + gpix;

    float xx = bx + (float)(k - 4) + extb[(size_t)(2 * k) * kHW];
    float yy = by + extb[(size_t)(2 * k + 1) * kHW];
    float xf = floorf(xx), yf = floorf(yy);
    float fx = xx - xf, fy = yy - yf;
    int ix0 = (int)xf, iy0 = (int)yf;
    int ix1 = ix0 + 1, iy1 = iy0 + 1;
    bool vx0 = (ix0 >= 0) && (ix0 < kW);
    bool vx1 = (ix1 >= 0) && (ix1 < kW);
    bool vy0 = (iy0 >= 0) && (iy0 < kH);
    bool vy1 = (iy1 >= 0) && (iy1 < kH);
    int xc0 = min(max(ix0, 0), kW - 1);
    int xc1 = min(max(ix1, 0), kW - 1);
    int yc0 = min(max(iy0, 0), kH - 1);
    int yc1 = min(max(iy1, 0), kH - 1);
    float wx0 = 1.f - fx, wy0 = 1.f - fy;
    TapMeta m;
    m.off.x = (yc0 * kW + xc0) * kC;
    m.off.y = (yc0 * kW + xc1) * kC;
    m.off.z = (yc1 * kW + xc0) * kC;
    m.off.w = (yc1 * kW + xc1) * kC;
    m.wgt.x = wx0 * wy0 * ((vx0 && vy0) ? 1.f : 0.f);
    m.wgt.y = fx  * wy0 * ((vx1 && vy0) ? 1.f : 0.f);
    m.wgt.z = wx0 * fy  * ((vx0 && vy1) ? 1.f : 0.f);
    m.wgt.w = fx  * fy  * ((vx1 && vy1) ? 1.f : 0.f);
    smeta[t] = m;
  }

  // left fp32 -> fp16 into LDS: px-major, contiguous 2B across threads
  // (2 lanes/dword = free alias).
  {
    float lv[8] = {lv0.x, lv0.y, lv0.z, lv0.w, lv1.x, lv1.y, lv1.z, lv1.w};
    #pragma unroll
    for (int j = 0; j < 8; ++j)
      smleft[j][t] = (_Float16)lv[j];
  }

  int wv   = t >> 6;                    // wave in block 0..3
  int lane = t & 63;
  int p    = lane >> 5;                 // pixel cluster 0..1
  int cl   = lane & 31;                 // channel-lane: owns channels cl*8..cl*8+7
  int pix  = pix0 + wv * 2 + p;

  const _Float16* Rb = right_t + (size_t)b * kPlane + cl * 8;

  __syncthreads();

  half8_t l8 = *(const half8_t*)&smleft[wv * 2 + p][cl * 8];
  const TapMeta* mp = smeta + (wv * 2 + p) * kK;   // LDS, broadcast reads

  float rr[kK];

  #pragma unroll
  for (int kb = 0; kb < kK; kb += 3) {
    int4   off[3];
    float4 wv4[3];
    #pragma unroll
    for (int j = 0; j < 3; ++j) {
      off[j] = mp[kb + j].off;
      wv4[j] = mp[kb + j].wgt;
    }
    half8_t tp[3][4];
    #pragma unroll
    for (int j = 0; j < 3; ++j) {
      tp[j][0] = *(const half8_t*)(Rb + off[j].x);
      tp[j][1] = *(const half8_t*)(Rb + off[j].y);
      tp[j][2] = *(const half8_t*)(Rb + off[j].z);
      tp[j][3] = *(const half8_t*)(Rb + off[j].w);
    }
    #pragma unroll
    for (int j = 0; j < 3; ++j) {
      float d00 = dot8(tp[j][0], l8, 0.f);
      float d01 = dot8(tp[j][1], l8, 0.f);
      float d10 = dot8(tp[j][2], l8, 0.f);
      float d11 = dot8(tp[j][3], l8, 0.f);
      float r = wv4[j].x * d00 + wv4[j].y * d01 + wv4[j].z * d10 + wv4[j].w * d11;
      r += __shfl_xor(r, 1);
      r += __shfl_xor(r, 2);
      r += __shfl_xor(r, 4);
      rr[kb + j] = r;           // all lanes hold the group sum
    }
  }

  // single masked store block: exec mask changes once
  int g = cl >> 3;
  if ((cl & 7) == 0) {
    float* outp = out + ((size_t)b * kG + g) * kK * kHW + pix;
    #pragma unroll
    for (int k = 0; k < kK; ++k)
      outp[(size_t)k * kHW] = rr[k] * (1.f / kGC);
  }
}

// ---- fallback (round-2 kernel) if workspace too small ----
__global__ __launch_bounds__(256) void crestereo_corr_fallback(
    const float* __restrict__ left, const float* __restrict__ right,
    const float* __restrict__ flow, const float* __restrict__ extra,
    float* __restrict__ out)
{
  int t = blockIdx.x * blockDim.x + threadIdx.x;
  int w = t % kW;
  int h = (t / kW) % kH;
  int k = (t / kHW) % kK;
  int g = (t / (kHW * kK)) % kG;
  int b = t / (kHW * kK * kG);

  int pix = h * kW + w;
  const float* flowb = flow + b * 2 * kHW + pix;
  float x = (float)(w + (k - 4)) + flowb[0];
  float y = (float)h + flowb[kHW];
  const float* extb = extra + (size_t)(b * 2 * kK + 2 * k) * kHW + pix;
  x += extb[0];
  y += extb[kHW];

  float xf = floorf(x), yf = floorf(y);
  float fx = x - xf, fy = y - yf;
  int ix0 = (int)xf, iy0 = (int)yf;
  int ix1 = ix0 + 1, iy1 = iy0 + 1;
  bool vx0 = (ix0 >= 0) && (ix0 < kW);
  bool vx1 = (ix1 >= 0) && (ix1 < kW);
  bool vy0 = (iy0 >= 0) && (iy0 < kH);
  bool vy1 = (iy1 >= 0) && (iy1 < kH);
  int xc0 = min(max(ix0, 0), kW - 1);
  int xc1 = min(max(ix1, 0), kW - 1);
  int yc0 = min(max(iy0, 0), kH - 1);
  int yc1 = min(max(iy1, 0), kH - 1);
  float wx0 = 1.f - fx, wy0 = 1.f - fy;
  float w00 = wx0 * wy0 * ((vx0 && vy0) ? 1.f : 0.f);
  float w01 = fx  * wy0 * ((vx1 && vy0) ? 1.f : 0.f);
  float w10 = wx0 * fy  * ((vx0 && vy1) ? 1.f : 0.f);
  float w11 = fx  * fy  * ((vx1 && vy1) ? 1.f : 0.f);
  int idx = yc0 * kW + xc0;
  int dx  = xc1 - xc0;
  int dyw = (yc1 - yc0) * kW;

  const float* Rb = right + (size_t)(b * kC + g * kGC) * kHW + idx;
  const float* Lb = left  + (size_t)(b * kC + g * kGC) * kHW + pix;

  float acc = 0.f;
  #pragma unroll 4
  for (int c = 0; c < kGC; ++c) {
    const float* Rc = Rb + (size_t)c * kHW;
    float l   = Lb[(size_t)c * kHW];
    acc += l * (w00 * Rc[0] + w01 * Rc[dx] + w10 * Rc[dyw] + w11 * Rc[dx + dyw]);
  }
  out[(size_t)((b * kG + g) * kK + k) * kHW + pix] = acc * (1.f / kGC);
}

extern "C" void kernel_launch(void* const* d_in, const int* in_sizes, int n_in,
                              void* d_out, int out_size, void* d_ws, size_t ws_size,
                              hipStream_t stream) {
  const float* left  = (const float*)d_in[0];
  const float* right = (const float*)d_in[1];
  const float* flow  = (const float*)d_in[2];
  const float* extra = (const float*)d_in[3];
  float* out = (float*)d_out;

  size_t t_bytes = (size_t)kB * kPlane * sizeof(_Float16);   // 18.9 MB (right_t)
  if (ws_size >= t_bytes) {
    _Float16* right_t = (_Float16*)d_ws;

    prepass_kernel<<<kTransBlocks, 256, 0, stream>>>(right, right_t);
    corr_fp16_kernel<<<kCorrBlocks, 256, 0, stream>>>(
        right_t, left, flow, extra, out);
  } else {
    int total = kB * kG * kK * kH * kW;
    crestereo_corr_fallback<<<(total + 255) / 256, 256, 0, stream>>>(
        left, right, flow, extra, out);
  }
}